// Round 1
// baseline (375.753 us; speedup 1.0000x reference)
//
#include <hip/hip_runtime.h>
#include <stdint.h>

typedef __bf16 bf16x8 __attribute__((ext_vector_type(8)));
typedef float f32x4 __attribute__((ext_vector_type(4)));

#define LOG2E 1.44269504088896340736f
#define ATT_SCALE 0.125f
#define SWZ(row, colb) ((colb) ^ (((row) & 7) << 4))

__device__ __forceinline__ unsigned short f2bf(float f) {
  unsigned int x = __float_as_uint(f);
  x += 0x7fffu + ((x >> 16) & 1u);
  return (unsigned short)(x >> 16);
}

// ---------------- fp32 -> bf16 convert (weights) ----------------
__global__ __launch_bounds__(256) void cvt_f32_bf16(const float* __restrict__ in,
                                                    unsigned short* __restrict__ out, int n) {
  int i = (blockIdx.x * 256 + threadIdx.x) * 4;
  if (i >= n) return;
  float4 v = *(const float4*)(in + i);
  ushort4 o;
  o.x = f2bf(v.x); o.y = f2bf(v.y); o.z = f2bf(v.z); o.w = f2bf(v.w);
  *(ushort4*)(out + i) = o;
}

// ---------------- [B][C][T] f32 -> [B][T][C] bf16 transpose ----------------
__global__ __launch_bounds__(256) void transpose_cvt(const float* __restrict__ in,
                                                     unsigned short* __restrict__ out,
                                                     int C, int T) {
  __shared__ unsigned short tile[32][33];
  int b = blockIdx.z;
  int t0 = blockIdx.x * 32, c0 = blockIdx.y * 32;
  int tx = threadIdx.x & 31, ty = threadIdx.x >> 5;
  const float* src = in + ((size_t)b * C + c0) * T + t0;
  #pragma unroll
  for (int i = 0; i < 4; ++i) {
    int cc = ty + i * 8;
    tile[cc][tx] = f2bf(src[(size_t)cc * T + tx]);
  }
  __syncthreads();
  unsigned short* dst = out + ((size_t)b * T + t0) * C + c0;
  #pragma unroll
  for (int i = 0; i < 4; ++i) {
    int tt = ty + i * 8;
    dst[(size_t)tt * C + tx] = tile[tx][tt];
  }
}

// ---------------- NT GEMM: C[m][n] = sum_k A[m][k]*B[n][k] (+bias) ----------------
// A: [M][K] bf16 rows (ldA), B: [N][K] bf16 rows (ldB). M,N mult of 128, K mult of 64.
// BIAS_MODE: 0 none, 1 bias[m], 2 bias[n]. OUT_BF16: 1 -> ushort out, 0 -> float out.
template <int OUT_BF16, int BIAS_MODE>
__global__ __launch_bounds__(256) void gemm_nt(
    const unsigned short* __restrict__ A, size_t sAb, int ldA,
    const unsigned short* __restrict__ B, size_t sBb, int ldB,
    void* __restrict__ C, size_t sCb, int ldC,
    const float* __restrict__ bias, int K) {
  __shared__ char lds[2 * 16384];  // As 128x64 bf16, Bs 128x64 bf16 (swizzled)
  char* As = lds;
  char* Bs = lds + 16384;
  const int tid = threadIdx.x;
  const int l = tid & 63, w = tid >> 6;
  const int g = l >> 4, j = l & 15;
  const int wr = w >> 1, wc = w & 1;
  const int m0 = blockIdx.y * 128, n0 = blockIdx.x * 128;
  const unsigned short* Ab = A + (size_t)blockIdx.z * sAb;
  const unsigned short* Bb = B + (size_t)blockIdx.z * sBb;

  f32x4 acc[4][4] = {};

  for (int k0 = 0; k0 < K; k0 += 64) {
    __syncthreads();
    #pragma unroll
    for (int p = 0; p < 4; ++p) {
      int u = p * 256 + tid;
      int row = u >> 3, ch = u & 7;
      uint4 va = *(const uint4*)(Ab + (size_t)(m0 + row) * ldA + k0 + ch * 8);
      *(uint4*)(As + row * 128 + SWZ(row, ch * 16)) = va;
      uint4 vb = *(const uint4*)(Bb + (size_t)(n0 + row) * ldB + k0 + ch * 8);
      *(uint4*)(Bs + row * 128 + SWZ(row, ch * 16)) = vb;
    }
    __syncthreads();
    #pragma unroll
    for (int k2 = 0; k2 < 2; ++k2) {
      bf16x8 af[4], bfr[4];
      #pragma unroll
      for (int mf = 0; mf < 4; ++mf) {
        int row = wr * 64 + mf * 16 + j;
        af[mf] = *(const bf16x8*)(As + row * 128 + SWZ(row, k2 * 64 + g * 16));
      }
      #pragma unroll
      for (int nf = 0; nf < 4; ++nf) {
        int row = wc * 64 + nf * 16 + j;
        bfr[nf] = *(const bf16x8*)(Bs + row * 128 + SWZ(row, k2 * 64 + g * 16));
      }
      #pragma unroll
      for (int mf = 0; mf < 4; ++mf)
        #pragma unroll
        for (int nf = 0; nf < 4; ++nf)
          acc[mf][nf] = __builtin_amdgcn_mfma_f32_16x16x32_bf16(af[mf], bfr[nf], acc[mf][nf], 0, 0, 0);
    }
  }

  #pragma unroll
  for (int mf = 0; mf < 4; ++mf) {
    #pragma unroll
    for (int r = 0; r < 4; ++r) {
      int m = m0 + wr * 64 + mf * 16 + g * 4 + r;
      float bm = (BIAS_MODE == 1) ? bias[m] : 0.f;
      #pragma unroll
      for (int nf = 0; nf < 4; ++nf) {
        int n = n0 + wc * 64 + nf * 16 + j;
        float val = acc[mf][nf][r] + bm + ((BIAS_MODE == 2) ? bias[n] : 0.f);
        size_t off = (size_t)blockIdx.z * sCb + (size_t)m * ldC + n;
        if (OUT_BF16) ((unsigned short*)C)[off] = f2bf(val);
        else ((float*)C)[off] = val;
      }
    }
  }
}

// ---------------- flash attention ----------------
// QT/KT: [B][T][1024] bf16 (head h cols h*64..h*64+63); V: [B][1024][T] bf16.
// OT: [B][T][1024] bf16. grid: (T/64, B*H), block 256 (4 waves, 16 q-rows each).
__global__ __launch_bounds__(256) void attn_kernel(const unsigned short* __restrict__ QT,
                                                   const unsigned short* __restrict__ KT,
                                                   const unsigned short* __restrict__ V,
                                                   unsigned short* __restrict__ OT) {
  __shared__ char lds[4 * 8192];
  char* Qs = lds;
  char* Ks = lds + 8192;
  char* Vs = lds + 16384;
  char* Ps = lds + 24576;
  const int b = blockIdx.y >> 4, h = blockIdx.y & 15;
  const int t0 = blockIdx.x * 64;
  const int tid = threadIdx.x, l = tid & 63, w = tid >> 6;
  const int g = l >> 4, j = l & 15;

  // stage Q tile [64 t][64 k]
  const unsigned short* Qbase = QT + ((size_t)(b * 2048 + t0)) * 1024 + h * 64;
  #pragma unroll
  for (int p = 0; p < 2; ++p) {
    int u = p * 256 + tid;
    int row = u >> 3, ch = u & 7;
    uint4 v = *(const uint4*)(Qbase + (size_t)row * 1024 + ch * 8);
    *(uint4*)(Qs + row * 128 + SWZ(row, ch * 16)) = v;
  }
  __syncthreads();
  bf16x8 aq[2];
  #pragma unroll
  for (int k2 = 0; k2 < 2; ++k2) {
    int row = w * 16 + j;
    aq[k2] = *(const bf16x8*)(Qs + row * 128 + SWZ(row, k2 * 64 + g * 16));
  }

  f32x4 o[4] = {};
  float mrun[4], lrun[4];
  #pragma unroll
  for (int r = 0; r < 4; ++r) { mrun[r] = -__builtin_inff(); lrun[r] = 0.f; }

  const unsigned short* Kbase = KT + ((size_t)b * 2048) * 1024 + h * 64;
  const unsigned short* Vbase = V + ((size_t)(b * 1024 + h * 64)) * 2048;

  for (int s0 = 0; s0 < 2048; s0 += 64) {
    // stage K [64 s][64 k] and V [64 k][64 s]
    #pragma unroll
    for (int p = 0; p < 2; ++p) {
      int u = p * 256 + tid;
      int row = u >> 3, ch = u & 7;
      uint4 vk = *(const uint4*)(Kbase + (size_t)(s0 + row) * 1024 + ch * 8);
      *(uint4*)(Ks + row * 128 + SWZ(row, ch * 16)) = vk;
      uint4 vv = *(const uint4*)(Vbase + (size_t)row * 2048 + s0 + ch * 8);
      *(uint4*)(Vs + row * 128 + SWZ(row, ch * 16)) = vv;
    }
    __syncthreads();

    // scores: [16 t][64 s] per wave
    f32x4 sc[4] = {};
    #pragma unroll
    for (int k2 = 0; k2 < 2; ++k2) {
      #pragma unroll
      for (int nf = 0; nf < 4; ++nf) {
        int row = nf * 16 + j;
        bf16x8 bk = *(const bf16x8*)(Ks + row * 128 + SWZ(row, k2 * 64 + g * 16));
        sc[nf] = __builtin_amdgcn_mfma_f32_16x16x32_bf16(aq[k2], bk, sc[nf], 0, 0, 0);
      }
    }

    // online softmax per row (row = w*16 + g*4 + r, cols j + 16*nf across 16 lanes)
    #pragma unroll
    for (int r = 0; r < 4; ++r) {
      float mx = fmaxf(fmaxf(sc[0][r], sc[1][r]), fmaxf(sc[2][r], sc[3][r]));
      #pragma unroll
      for (int d = 1; d < 16; d <<= 1) mx = fmaxf(mx, __shfl_xor(mx, d));
      mx *= ATT_SCALE;
      float mnew = fmaxf(mrun[r], mx);
      float fac = exp2f((mrun[r] - mnew) * LOG2E);
      float rs = 0.f;
      int prow = w * 16 + g * 4 + r;
      #pragma unroll
      for (int nf = 0; nf < 4; ++nf) {
        float p = exp2f((sc[nf][r] * ATT_SCALE - mnew) * LOG2E);
        rs += p;
        *(unsigned short*)(Ps + prow * 128 + SWZ(prow, (nf * 16 + j) * 2)) = f2bf(p);
        o[nf][r] *= fac;
      }
      #pragma unroll
      for (int d = 1; d < 16; d <<= 1) rs += __shfl_xor(rs, d);
      lrun[r] = lrun[r] * fac + rs;
      mrun[r] = mnew;
    }

    // PV: o[16 t][64 k] += P[16 t][64 s] * V[64 k][64 s]^T
    #pragma unroll
    for (int k2 = 0; k2 < 2; ++k2) {
      int prow = w * 16 + j;
      bf16x8 pa = *(const bf16x8*)(Ps + prow * 128 + SWZ(prow, k2 * 64 + g * 16));
      #pragma unroll
      for (int nf = 0; nf < 4; ++nf) {
        int vrow = nf * 16 + j;
        bf16x8 vb = *(const bf16x8*)(Vs + vrow * 128 + SWZ(vrow, k2 * 64 + g * 16));
        o[nf] = __builtin_amdgcn_mfma_f32_16x16x32_bf16(pa, vb, o[nf], 0, 0, 0);
      }
    }
    __syncthreads();
  }

  unsigned short* Obase = OT + ((size_t)(b * 2048 + t0)) * 1024 + h * 64;
  #pragma unroll
  for (int r = 0; r < 4; ++r) {
    float inv = 1.f / lrun[r];
    int trow = w * 16 + g * 4 + r;
    #pragma unroll
    for (int nf = 0; nf < 4; ++nf) {
      Obase[(size_t)trow * 1024 + nf * 16 + j] = f2bf(o[nf][r] * inv);
    }
  }
}

// ---------------- launch ----------------
extern "C" void kernel_launch(void* const* d_in, const int* in_sizes, int n_in,
                              void* d_out, int out_size, void* d_ws, size_t ws_size,
                              hipStream_t stream) {
  const float* x  = (const float*)d_in[0];
  const float* c  = (const float*)d_in[1];
  const float* Wq = (const float*)d_in[2];
  const float* bq = (const float*)d_in[3];
  const float* Wk = (const float*)d_in[4];
  const float* bk = (const float*)d_in[5];
  const float* Wv = (const float*)d_in[6];
  const float* bv = (const float*)d_in[7];
  const float* Wo = (const float*)d_in[8];
  const float* bo = (const float*)d_in[9];

  const size_t MB = 1024 * 1024;
  char* ws = (char*)d_ws;
  unsigned short* wqb = (unsigned short*)(ws + 0 * MB);
  unsigned short* wkb = (unsigned short*)(ws + 2 * MB);
  unsigned short* wvb = (unsigned short*)(ws + 4 * MB);
  unsigned short* wob = (unsigned short*)(ws + 6 * MB);
  unsigned short* xT  = (unsigned short*)(ws + 8 * MB);   // [B][T][C] bf16, 16MB
  unsigned short* cT  = (unsigned short*)(ws + 24 * MB);
  unsigned short* QT  = (unsigned short*)(ws + 40 * MB);
  unsigned short* KT  = (unsigned short*)(ws + 56 * MB);
  unsigned short* Vb  = (unsigned short*)(ws + 72 * MB);  // [B][C][T] bf16
  unsigned short* OT  = xT;  // reuse: x dead after QT gemm

  cvt_f32_bf16<<<1024, 256, 0, stream>>>(Wq, wqb, 1 << 20);
  cvt_f32_bf16<<<1024, 256, 0, stream>>>(Wk, wkb, 1 << 20);
  cvt_f32_bf16<<<1024, 256, 0, stream>>>(Wv, wvb, 1 << 20);
  cvt_f32_bf16<<<1024, 256, 0, stream>>>(Wo, wob, 1 << 20);
  transpose_cvt<<<dim3(64, 32, 4), 256, 0, stream>>>(x, xT, 1024, 2048);
  transpose_cvt<<<dim3(64, 32, 4), 256, 0, stream>>>(c, cT, 1024, 2048);

  const size_t sBT = (size_t)2048 * 1024;
  // QT[t][o] = sum_c xT[t][c] * Wq[o][c] + bq[o]
  gemm_nt<1, 2><<<dim3(8, 16, 4), 256, 0, stream>>>(xT, sBT, 1024, wqb, 0, 1024, QT, sBT, 1024, bq, 1024);
  // KT[s][o] = sum_c cT[s][c] * Wk[o][c] + bk[o]
  gemm_nt<1, 2><<<dim3(8, 16, 4), 256, 0, stream>>>(cT, sBT, 1024, wkb, 0, 1024, KT, sBT, 1024, bk, 1024);
  // V[o][t] = sum_c Wv[o][c] * cT[t][c] + bv[o]
  gemm_nt<1, 1><<<dim3(16, 8, 4), 256, 0, stream>>>(wvb, 0, 1024, cT, sBT, 1024, Vb, sBT, 2048, bv, 1024);

  attn_kernel<<<dim3(32, 64), 256, 0, stream>>>(QT, KT, Vb, OT);

  // out[o][t] = sum_c Wo[o][c] * OT[t][c] + bo[o]  (fp32 out)
  gemm_nt<0, 1><<<dim3(16, 8, 4), 256, 0, stream>>>(wob, 0, 1024, OT, sBT, 1024, d_out, sBT, 2048, bo, 1024);
}

// Round 2
// 246.814 us; speedup vs baseline: 1.5224x; 1.5224x over previous
//
#include <hip/hip_runtime.h>
#include <stdint.h>

typedef __bf16 bf16x8 __attribute__((ext_vector_type(8)));
typedef float f32x4 __attribute__((ext_vector_type(4)));
typedef float f32x16 __attribute__((ext_vector_type(16)));
typedef unsigned u32x2 __attribute__((ext_vector_type(2)));
typedef unsigned u32x4 __attribute__((ext_vector_type(4)));

#define LOG2E 1.44269504088896340736f
#define ATT_SCALE 0.125f
#define CL (ATT_SCALE * LOG2E)
#define SWZ(row, colb) ((colb) ^ (((row) & 7) << 4))

__device__ __forceinline__ unsigned short f2bf(float f) {
  unsigned int x = __float_as_uint(f);
  x += 0x7fffu + ((x >> 16) & 1u);
  return (unsigned short)(x >> 16);
}

__device__ __forceinline__ unsigned cvtpk(float lo, float hi) {
  unsigned r;
  asm("v_cvt_pk_bf16_f32 %0, %1, %2" : "=v"(r) : "v"(lo), "v"(hi));
  return r;
}

// permlane32_swap: r[0] = {lanes<32: a(own); lanes>=32: b(partner-lo)}
//                  r[1] = {lanes<32: a(partner-hi); lanes>=32: b(own)}
__device__ __forceinline__ u32x2 plswap(unsigned a, unsigned b) {
#if __has_builtin(__builtin_amdgcn_permlane32_swap)
  return __builtin_amdgcn_permlane32_swap(a, b, false, false);
#else
  unsigned ax = (unsigned)__shfl_xor((int)a, 32);
  unsigned bx = (unsigned)__shfl_xor((int)b, 32);
  int hi = (threadIdx.x & 32) ? 1 : 0;
  u32x2 r;
  r[0] = hi ? bx : a;
  r[1] = hi ? b : ax;
  return r;
#endif
}

// ---------------- fp32 -> bf16 convert (weights) ----------------
__global__ __launch_bounds__(256) void cvt_f32_bf16(const float* __restrict__ in,
                                                    unsigned short* __restrict__ out, int n) {
  int i = (blockIdx.x * 256 + threadIdx.x) * 4;
  if (i >= n) return;
  float4 v = *(const float4*)(in + i);
  ushort4 o;
  o.x = f2bf(v.x); o.y = f2bf(v.y); o.z = f2bf(v.z); o.w = f2bf(v.w);
  *(ushort4*)(out + i) = o;
}

// ---------------- [B][C][T] f32 -> [B][T][C] bf16 transpose ----------------
__global__ __launch_bounds__(256) void transpose_cvt(const float* __restrict__ in,
                                                     unsigned short* __restrict__ out,
                                                     int C, int T) {
  __shared__ unsigned short tile[32][33];
  int b = blockIdx.z;
  int t0 = blockIdx.x * 32, c0 = blockIdx.y * 32;
  int tx = threadIdx.x & 31, ty = threadIdx.x >> 5;
  const float* src = in + ((size_t)b * C + c0) * T + t0;
  #pragma unroll
  for (int i = 0; i < 4; ++i) {
    int cc = ty + i * 8;
    tile[cc][tx] = f2bf(src[(size_t)cc * T + tx]);
  }
  __syncthreads();
  unsigned short* dst = out + ((size_t)b * T + t0) * C + c0;
  #pragma unroll
  for (int i = 0; i < 4; ++i) {
    int tt = ty + i * 8;
    dst[(size_t)tt * C + tx] = tile[tx][tt];
  }
}

// ---------------- NT GEMM: C[m][n] = sum_k A[m][k]*B[n][k] (+bias) ----------------
template <int OUT_BF16, int BIAS_MODE>
__global__ __launch_bounds__(256) void gemm_nt(
    const unsigned short* __restrict__ A, size_t sAb, int ldA,
    const unsigned short* __restrict__ B, size_t sBb, int ldB,
    void* __restrict__ C, size_t sCb, int ldC,
    const float* __restrict__ bias, int K) {
  __shared__ __align__(16) char lds[2 * 16384];
  char* As = lds;
  char* Bs = lds + 16384;
  const int tid = threadIdx.x;
  const int l = tid & 63, w = tid >> 6;
  const int g = l >> 4, j = l & 15;
  const int wr = w >> 1, wc = w & 1;
  const int m0 = blockIdx.y * 128, n0 = blockIdx.x * 128;
  const unsigned short* Ab = A + (size_t)blockIdx.z * sAb;
  const unsigned short* Bb = B + (size_t)blockIdx.z * sBb;

  f32x4 acc[4][4] = {};

  for (int k0 = 0; k0 < K; k0 += 64) {
    __syncthreads();
    #pragma unroll
    for (int p = 0; p < 4; ++p) {
      int u = p * 256 + tid;
      int row = u >> 3, ch = u & 7;
      uint4 va = *(const uint4*)(Ab + (size_t)(m0 + row) * ldA + k0 + ch * 8);
      *(uint4*)(As + row * 128 + SWZ(row, ch * 16)) = va;
      uint4 vb = *(const uint4*)(Bb + (size_t)(n0 + row) * ldB + k0 + ch * 8);
      *(uint4*)(Bs + row * 128 + SWZ(row, ch * 16)) = vb;
    }
    __syncthreads();
    #pragma unroll
    for (int k2 = 0; k2 < 2; ++k2) {
      bf16x8 af[4], bfr[4];
      #pragma unroll
      for (int mf = 0; mf < 4; ++mf) {
        int row = wr * 64 + mf * 16 + j;
        af[mf] = *(const bf16x8*)(As + row * 128 + SWZ(row, k2 * 64 + g * 16));
      }
      #pragma unroll
      for (int nf = 0; nf < 4; ++nf) {
        int row = wc * 64 + nf * 16 + j;
        bfr[nf] = *(const bf16x8*)(Bs + row * 128 + SWZ(row, k2 * 64 + g * 16));
      }
      #pragma unroll
      for (int mf = 0; mf < 4; ++mf)
        #pragma unroll
        for (int nf = 0; nf < 4; ++nf)
          acc[mf][nf] = __builtin_amdgcn_mfma_f32_16x16x32_bf16(af[mf], bfr[nf], acc[mf][nf], 0, 0, 0);
    }
  }

  #pragma unroll
  for (int mf = 0; mf < 4; ++mf) {
    #pragma unroll
    for (int r = 0; r < 4; ++r) {
      int m = m0 + wr * 64 + mf * 16 + g * 4 + r;
      float bm = (BIAS_MODE == 1) ? bias[m] : 0.f;
      #pragma unroll
      for (int nf = 0; nf < 4; ++nf) {
        int n = n0 + wc * 64 + nf * 16 + j;
        float val = acc[mf][nf][r] + bm + ((BIAS_MODE == 2) ? bias[n] : 0.f);
        size_t off = (size_t)blockIdx.z * sCb + (size_t)m * ldC + n;
        if (OUT_BF16) ((unsigned short*)C)[off] = f2bf(val);
        else ((float*)C)[off] = val;
      }
    }
  }
}

// ---------------- flash attention v2: swapped QK^T, 32x32x16, in-reg softmax ----
// QT/KT: [B][2048][1024] bf16 (head h cols h*64..); V: [B][1024][2048] bf16.
// OT: [B][2048][1024] bf16. grid: 512 1-D blocks of 256 (4 waves x 64 q-rows).
__global__ __launch_bounds__(256, 2) void attn_kernel2(const unsigned short* __restrict__ QT,
                                                       const unsigned short* __restrict__ KT,
                                                       const unsigned short* __restrict__ V,
                                                       unsigned short* __restrict__ OT) {
  __shared__ __align__(16) char Ks[8192];   // K tile [64 s][64 k] bf16, swizzled
  __shared__ __align__(16) char Vs[8192];   // V tile [64 ko][64 s] bf16, swizzled
  __shared__ float lbuf[4][32];

  // XCD-grouping swizzle: all 8 t-blocks of one (b,h) land on one XCD's L2.
  const int fid = blockIdx.x;          // 0..511
  const int xcd = fid & 7, idx = fid >> 3;
  const int bh = ((idx & 7) << 3) | xcd;   // bh & 7 == xcd
  const int xblk = idx >> 3;               // 0..7
  const int b = bh >> 4, h = bh & 15;

  const int tid = threadIdx.x;
  const int w = tid >> 6, l = tid & 63, lo5 = l & 31, hi = l >> 5;
  const int tq0 = xblk * 256 + w * 64;

  // Q fragments (B-operand): lane holds q-row (tq0+tb*32+lo5), k = kb*16+hi*8..+7
  bf16x8 q[2][4];
  {
    const unsigned short* Qb = QT + ((size_t)(b * 2048 + tq0 + lo5)) * 1024 + h * 64 + hi * 8;
    #pragma unroll
    for (int tb = 0; tb < 2; ++tb)
      #pragma unroll
      for (int kb = 0; kb < 4; ++kb)
        q[tb][kb] = *(const bf16x8*)(Qb + (size_t)tb * 32 * 1024 + kb * 16);
  }

  f32x16 o[2][2] = {};
  float mC[2] = {0.f, 0.f};   // running max in exp2 domain (score*CL); init 0 (defer-max)
  float lr[2] = {0.f, 0.f};   // per-lane partial sum (lane's 32-s half of its row)

  const unsigned short* Kg0 = KT + ((size_t)b * 2048) * 1024 + h * 64;
  const unsigned short* Vg0 = V + ((size_t)(b * 1024 + h * 64)) * 2048;

  for (int s0 = 0; s0 < 2048; s0 += 64) {
    __syncthreads();
    // stage K,V: linear LDS writes, pre-swizzled global chunk (m173 pattern)
    #pragma unroll
    for (int p = 0; p < 2; ++p) {
      int u = p * 256 + tid;
      int row = u >> 3, slot = u & 7;
      int ch = slot ^ (row & 7);
      uint4 vk = *(const uint4*)(Kg0 + (size_t)(s0 + row) * 1024 + ch * 8);
      *(uint4*)(Ks + row * 128 + slot * 16) = vk;
      uint4 vv = *(const uint4*)(Vg0 + (size_t)row * 2048 + s0 + ch * 8);
      *(uint4*)(Vs + row * 128 + slot * 16) = vv;
    }
    __syncthreads();

    // K A-fragments: row = sblk*32+lo5, k = kb*16+hi*8
    bf16x8 ka[2][4];
    #pragma unroll
    for (int sblk = 0; sblk < 2; ++sblk)
      #pragma unroll
      for (int kb = 0; kb < 4; ++kb) {
        int row = sblk * 32 + lo5;
        ka[sblk][kb] = *(const bf16x8*)(Ks + row * 128 + SWZ(row, kb * 32 + hi * 16));
      }

    u32x4 pa[2][4];  // PV A-frags per tb, sb=0..3 (s-chunks of 16)
    #pragma unroll
    for (int tb = 0; tb < 2; ++tb) {
      f32x16 p0 = {}, p1 = {};
      #pragma unroll
      for (int kb = 0; kb < 4; ++kb) {
        p0 = __builtin_amdgcn_mfma_f32_32x32x16_bf16(ka[0][kb], q[tb][kb], p0, 0, 0, 0);
        p1 = __builtin_amdgcn_mfma_f32_32x32x16_bf16(ka[1][kb], q[tb][kb], p1, 0, 0, 0);
      }
      // row max (lane pair l / l+32 holds the full 64-s row)
      float mx = p0[0];
      #pragma unroll
      for (int r = 1; r < 16; ++r) mx = fmaxf(mx, p0[r]);
      #pragma unroll
      for (int r = 0; r < 16; ++r) mx = fmaxf(mx, p1[r]);
      u32x2 sw = plswap(__float_as_uint(mx), __float_as_uint(mx));
      mx = fmaxf(__uint_as_float(sw[0]), __uint_as_float(sw[1]));
      float pmaxC = mx * CL;
      if (__any(pmaxC > mC[tb] + 12.0f)) {  // rare rescale path
        float mn = fmaxf(mC[tb], pmaxC);
        float fac = exp2f(mC[tb] - mn);
        lr[tb] *= fac;
        mC[tb] = mn;
        if (hi == 0) lbuf[w][lo5] = fac;
        #pragma unroll
        for (int r = 0; r < 16; ++r) {
          float fr = lbuf[w][(r & 3) + 8 * (r >> 2) + 4 * hi];
          o[tb][0][r] *= fr;
          o[tb][1][r] *= fr;
        }
      }
      float ls = 0.f;
      float m = mC[tb];
      #pragma unroll
      for (int r = 0; r < 16; ++r) { float e = exp2f(fmaf(p0[r], CL, -m)); p0[r] = e; ls += e; }
      #pragma unroll
      for (int r = 0; r < 16; ++r) { float e = exp2f(fmaf(p1[r], CL, -m)); p1[r] = e; ls += e; }
      lr[tb] += ls;
      // pack P -> bf16 A-frags via cvt_pk + permlane32_swap
      {
        u32x2 ra = plswap(cvtpk(p0[0], p0[1]), cvtpk(p0[4], p0[5]));
        u32x2 rb = plswap(cvtpk(p0[2], p0[3]), cvtpk(p0[6], p0[7]));
        pa[tb][0] = (u32x4){ra[0], rb[0], ra[1], rb[1]};
        u32x2 rc = plswap(cvtpk(p0[8], p0[9]), cvtpk(p0[12], p0[13]));
        u32x2 rd = plswap(cvtpk(p0[10], p0[11]), cvtpk(p0[14], p0[15]));
        pa[tb][1] = (u32x4){rc[0], rd[0], rc[1], rd[1]};
        u32x2 re = plswap(cvtpk(p1[0], p1[1]), cvtpk(p1[4], p1[5]));
        u32x2 rf = plswap(cvtpk(p1[2], p1[3]), cvtpk(p1[6], p1[7]));
        pa[tb][2] = (u32x4){re[0], rf[0], re[1], rf[1]};
        u32x2 rg = plswap(cvtpk(p1[8], p1[9]), cvtpk(p1[12], p1[13]));
        u32x2 rh = plswap(cvtpk(p1[10], p1[11]), cvtpk(p1[14], p1[15]));
        pa[tb][3] = (u32x4){rg[0], rh[0], rg[1], rh[1]};
      }
    }

    // PV: o[tb][kb2] += P[t][s] * V[ko][s]^T
    #pragma unroll
    for (int sb = 0; sb < 4; ++sb)
      #pragma unroll
      for (int kb2 = 0; kb2 < 2; ++kb2) {
        int row = kb2 * 32 + lo5;
        bf16x8 vb = *(const bf16x8*)(Vs + row * 128 + SWZ(row, sb * 32 + hi * 16));
        o[0][kb2] = __builtin_amdgcn_mfma_f32_32x32x16_bf16(
            __builtin_bit_cast(bf16x8, pa[0][sb]), vb, o[0][kb2], 0, 0, 0);
        o[1][kb2] = __builtin_amdgcn_mfma_f32_32x32x16_bf16(
            __builtin_bit_cast(bf16x8, pa[1][sb]), vb, o[1][kb2], 0, 0, 0);
      }
  }

  // epilogue: combine row-sums across lane pair, broadcast 1/l, store
  #pragma unroll
  for (int tb = 0; tb < 2; ++tb) {
    u32x2 sw = plswap(__float_as_uint(lr[tb]), __float_as_uint(lr[tb]));
    float lt = __uint_as_float(sw[0]) + __uint_as_float(sw[1]);
    if (hi == 0) lbuf[w][lo5] = 1.0f / lt;
    unsigned short* Ob = OT + ((size_t)(b * 2048 + tq0 + tb * 32)) * 1024 + h * 64 + lo5;
    #pragma unroll
    for (int r = 0; r < 16; ++r) {
      int srow = (r & 3) + 8 * (r >> 2) + 4 * hi;
      float inv = lbuf[w][srow];
      Ob[(size_t)srow * 1024 + 0]  = f2bf(o[tb][0][r] * inv);
      Ob[(size_t)srow * 1024 + 32] = f2bf(o[tb][1][r] * inv);
    }
  }
}

// ---------------- launch ----------------
extern "C" void kernel_launch(void* const* d_in, const int* in_sizes, int n_in,
                              void* d_out, int out_size, void* d_ws, size_t ws_size,
                              hipStream_t stream) {
  const float* x  = (const float*)d_in[0];
  const float* c  = (const float*)d_in[1];
  const float* Wq = (const float*)d_in[2];
  const float* bq = (const float*)d_in[3];
  const float* Wk = (const float*)d_in[4];
  const float* bk = (const float*)d_in[5];
  const float* Wv = (const float*)d_in[6];
  const float* bv = (const float*)d_in[7];
  const float* Wo = (const float*)d_in[8];
  const float* bo = (const float*)d_in[9];

  const size_t MB = 1024 * 1024;
  char* ws = (char*)d_ws;
  unsigned short* wqb = (unsigned short*)(ws + 0 * MB);
  unsigned short* wkb = (unsigned short*)(ws + 2 * MB);
  unsigned short* wvb = (unsigned short*)(ws + 4 * MB);
  unsigned short* wob = (unsigned short*)(ws + 6 * MB);
  unsigned short* xT  = (unsigned short*)(ws + 8 * MB);   // [B][T][C] bf16, 16MB
  unsigned short* cT  = (unsigned short*)(ws + 24 * MB);
  unsigned short* QT  = (unsigned short*)(ws + 40 * MB);
  unsigned short* KT  = (unsigned short*)(ws + 56 * MB);
  unsigned short* Vb  = (unsigned short*)(ws + 72 * MB);  // [B][C][T] bf16
  unsigned short* OT  = xT;  // reuse: x dead after QT gemm

  cvt_f32_bf16<<<1024, 256, 0, stream>>>(Wq, wqb, 1 << 20);
  cvt_f32_bf16<<<1024, 256, 0, stream>>>(Wk, wkb, 1 << 20);
  cvt_f32_bf16<<<1024, 256, 0, stream>>>(Wv, wvb, 1 << 20);
  cvt_f32_bf16<<<1024, 256, 0, stream>>>(Wo, wob, 1 << 20);
  transpose_cvt<<<dim3(64, 32, 4), 256, 0, stream>>>(x, xT, 1024, 2048);
  transpose_cvt<<<dim3(64, 32, 4), 256, 0, stream>>>(c, cT, 1024, 2048);

  const size_t sBT = (size_t)2048 * 1024;
  gemm_nt<1, 2><<<dim3(8, 16, 4), 256, 0, stream>>>(xT, sBT, 1024, wqb, 0, 1024, QT, sBT, 1024, bq, 1024);
  gemm_nt<1, 2><<<dim3(8, 16, 4), 256, 0, stream>>>(cT, sBT, 1024, wkb, 0, 1024, KT, sBT, 1024, bk, 1024);
  gemm_nt<1, 1><<<dim3(16, 8, 4), 256, 0, stream>>>(wvb, 0, 1024, cT, sBT, 1024, Vb, sBT, 2048, bv, 1024);

  attn_kernel2<<<dim3(512), 256, 0, stream>>>(QT, KT, Vb, OT);

  gemm_nt<0, 1><<<dim3(16, 8, 4), 256, 0, stream>>>(wob, 0, 1024, OT, sBT, 1024, d_out, sBT, 2048, bo, 1024);
}

// Round 3
// 222.036 us; speedup vs baseline: 1.6923x; 1.1116x over previous
//
#include <hip/hip_runtime.h>
#include <stdint.h>

typedef __bf16 bf16x8 __attribute__((ext_vector_type(8)));
typedef float f32x4 __attribute__((ext_vector_type(4)));
typedef float f32x16 __attribute__((ext_vector_type(16)));
typedef unsigned u32x2 __attribute__((ext_vector_type(2)));
typedef unsigned u32x4 __attribute__((ext_vector_type(4)));

#define LOG2E 1.44269504088896340736f
#define ATT_SCALE 0.125f
#define CL (ATT_SCALE * LOG2E)
#define SWZ(row, colb) ((colb) ^ (((row) & 7) << 4))

#define GLOAD_LDS16(gp, lp)                                                  \
  __builtin_amdgcn_global_load_lds(                                          \
      (const __attribute__((address_space(1))) void*)(gp),                   \
      (__attribute__((address_space(3))) void*)(lp), 16, 0, 0)

__device__ __forceinline__ unsigned short f2bf(float f) {
  unsigned int x = __float_as_uint(f);
  x += 0x7fffu + ((x >> 16) & 1u);
  return (unsigned short)(x >> 16);
}

__device__ __forceinline__ float fexp2(float x) {
#if __has_builtin(__builtin_amdgcn_exp2f)
  return __builtin_amdgcn_exp2f(x);
#else
  return exp2f(x);
#endif
}

__device__ __forceinline__ unsigned cvtpk(float lo, float hi) {
  unsigned r;
  asm("v_cvt_pk_bf16_f32 %0, %1, %2" : "=v"(r) : "v"(lo), "v"(hi));
  return r;
}

__device__ __forceinline__ u32x2 plswap(unsigned a, unsigned b) {
#if __has_builtin(__builtin_amdgcn_permlane32_swap)
  return __builtin_amdgcn_permlane32_swap(a, b, false, false);
#else
  unsigned ax = (unsigned)__shfl_xor((int)a, 32);
  unsigned bx = (unsigned)__shfl_xor((int)b, 32);
  int hi = (threadIdx.x & 32) ? 1 : 0;
  u32x2 r;
  r[0] = hi ? bx : a;
  r[1] = hi ? b : ax;
  return r;
#endif
}

// ---------------- fp32 -> bf16 convert (weights), optional scale ----------------
__global__ __launch_bounds__(256) void cvt_f32_bf16(const float* __restrict__ in,
                                                    unsigned short* __restrict__ out,
                                                    int n, float scale) {
  int i = (blockIdx.x * 256 + threadIdx.x) * 4;
  if (i >= n) return;
  float4 v = *(const float4*)(in + i);
  ushort4 o;
  o.x = f2bf(v.x * scale); o.y = f2bf(v.y * scale);
  o.z = f2bf(v.z * scale); o.w = f2bf(v.w * scale);
  *(ushort4*)(out + i) = o;
}

// ---------------- [B][C][T] f32 -> [B][T][C] bf16 transpose ----------------
__global__ __launch_bounds__(256) void transpose_cvt(const float* __restrict__ in,
                                                     unsigned short* __restrict__ out,
                                                     int C, int T) {
  __shared__ unsigned short tile[32][33];
  int b = blockIdx.z;
  int t0 = blockIdx.x * 32, c0 = blockIdx.y * 32;
  int tx = threadIdx.x & 31, ty = threadIdx.x >> 5;
  const float* src = in + ((size_t)b * C + c0) * T + t0;
  #pragma unroll
  for (int i = 0; i < 4; ++i) {
    int cc = ty + i * 8;
    tile[cc][tx] = f2bf(src[(size_t)cc * T + tx]);
  }
  __syncthreads();
  unsigned short* dst = out + ((size_t)b * T + t0) * C + c0;
  #pragma unroll
  for (int i = 0; i < 4; ++i) {
    int tt = ty + i * 8;
    dst[(size_t)tt * C + tx] = tile[tx][tt];
  }
}

// ---------------- fused QKV GEMM (NT, 128x128 tile, global_load_lds staging) ----
// op0: QT[t][o] = xT[t][c]*Wq[o][c] + bq*CL ; op1: KT = cT*Wk + bk ;
// op2: Vb[o][t] = Wv[o][c]*cT[t][c] + bv. grid 1536 1-D, XCD-chunked.
__global__ __launch_bounds__(256) void qkv_gemm(
    const unsigned short* __restrict__ xT, const unsigned short* __restrict__ cT,
    const unsigned short* __restrict__ wq, const unsigned short* __restrict__ wk,
    const unsigned short* __restrict__ wv,
    const float* __restrict__ bq, const float* __restrict__ bk,
    const float* __restrict__ bv,
    unsigned short* __restrict__ QT, unsigned short* __restrict__ KT,
    unsigned short* __restrict__ Vb) {
  __shared__ __align__(16) char lds[2 * 16384];
  char* As = lds;
  char* Bs = lds + 16384;
  const size_t sBT = (size_t)2048 * 1024;

  const int id = (blockIdx.x & 7) * 192 + (blockIdx.x >> 3);  // XCD chunking
  const int op = id >> 9;
  const int r = id & 511;
  const int z = r >> 7;
  const unsigned short *A, *Bw;
  unsigned short* Cp;
  const float* bias;
  int m0, n0, ldC, bias_is_m;
  float bs;
  if (op == 2) {
    n0 = (r & 15) * 128; m0 = ((r >> 4) & 7) * 128;
    A = wv; Bw = cT + z * sBT; Cp = Vb + z * (size_t)1024 * 2048;
    bias = bv; ldC = 2048; bias_is_m = 1; bs = 1.0f;
  } else {
    n0 = (r & 7) * 128; m0 = ((r >> 3) & 15) * 128;
    A = (op == 0 ? xT : cT) + z * sBT;
    Bw = (op == 0 ? wq : wk);
    Cp = (op == 0 ? QT : KT) + z * sBT;
    bias = (op == 0 ? bq : bk); ldC = 1024; bias_is_m = 0;
    bs = (op == 0) ? CL : 1.0f;
  }

  const int tid = threadIdx.x;
  const int l = tid & 63, w = tid >> 6;
  const int g = l >> 4, j = l & 15;
  const int wr = w >> 1, wc = w & 1;
  const int srow = tid >> 3, sslot = tid & 7;   // staging row/slot (per 256-thread pass)

  f32x4 acc[4][4] = {};

  for (int k0 = 0; k0 < 1024; k0 += 64) {
    __syncthreads();
    #pragma unroll
    for (int p = 0; p < 4; ++p) {
      int row = p * 32 + srow;
      int ch = sslot ^ (row & 7);
      GLOAD_LDS16(A + (size_t)(m0 + row) * 1024 + k0 + ch * 8, As + (p * 256 + tid) * 16);
      GLOAD_LDS16(Bw + (size_t)(n0 + row) * 1024 + k0 + ch * 8, Bs + (p * 256 + tid) * 16);
    }
    __syncthreads();
    #pragma unroll
    for (int k2 = 0; k2 < 2; ++k2) {
      bf16x8 af[4], bfr[4];
      #pragma unroll
      for (int mf = 0; mf < 4; ++mf) {
        int row = wr * 64 + mf * 16 + j;
        af[mf] = *(const bf16x8*)(As + row * 128 + SWZ(row, k2 * 64 + g * 16));
      }
      #pragma unroll
      for (int nf = 0; nf < 4; ++nf) {
        int row = wc * 64 + nf * 16 + j;
        bfr[nf] = *(const bf16x8*)(Bs + row * 128 + SWZ(row, k2 * 64 + g * 16));
      }
      #pragma unroll
      for (int mf = 0; mf < 4; ++mf)
        #pragma unroll
        for (int nf = 0; nf < 4; ++nf)
          acc[mf][nf] = __builtin_amdgcn_mfma_f32_16x16x32_bf16(af[mf], bfr[nf], acc[mf][nf], 0, 0, 0);
    }
  }

  #pragma unroll
  for (int mf = 0; mf < 4; ++mf) {
    #pragma unroll
    for (int rr = 0; rr < 4; ++rr) {
      int m = m0 + wr * 64 + mf * 16 + g * 4 + rr;
      float bm = bias_is_m ? bias[m] * bs : 0.f;
      #pragma unroll
      for (int nf = 0; nf < 4; ++nf) {
        int n = n0 + wc * 64 + nf * 16 + j;
        float val = acc[mf][nf][rr] + bm + (bias_is_m ? 0.f : bias[n] * bs);
        Cp[(size_t)m * ldC + n] = f2bf(val);
      }
    }
  }
}

// ---------------- output projection GEMM: fp32 out ----------------
__global__ __launch_bounds__(256) void gemm_out(
    const unsigned short* __restrict__ Wo, const unsigned short* __restrict__ OT,
    float* __restrict__ Out, const float* __restrict__ bias) {
  __shared__ __align__(16) char lds[2 * 16384];
  char* As = lds;
  char* Bs = lds + 16384;
  const size_t sBT = (size_t)2048 * 1024;
  const int z = blockIdx.z;
  const int m0 = blockIdx.y * 128, n0 = blockIdx.x * 128;
  const unsigned short* A = Wo;
  const unsigned short* B = OT + z * sBT;
  float* Cp = Out + z * (size_t)1024 * 2048;

  const int tid = threadIdx.x;
  const int l = tid & 63, w = tid >> 6;
  const int g = l >> 4, j = l & 15;
  const int wr = w >> 1, wc = w & 1;
  const int srow = tid >> 3, sslot = tid & 7;

  f32x4 acc[4][4] = {};

  for (int k0 = 0; k0 < 1024; k0 += 64) {
    __syncthreads();
    #pragma unroll
    for (int p = 0; p < 4; ++p) {
      int row = p * 32 + srow;
      int ch = sslot ^ (row & 7);
      GLOAD_LDS16(A + (size_t)(m0 + row) * 1024 + k0 + ch * 8, As + (p * 256 + tid) * 16);
      GLOAD_LDS16(B + (size_t)(n0 + row) * 1024 + k0 + ch * 8, Bs + (p * 256 + tid) * 16);
    }
    __syncthreads();
    #pragma unroll
    for (int k2 = 0; k2 < 2; ++k2) {
      bf16x8 af[4], bfr[4];
      #pragma unroll
      for (int mf = 0; mf < 4; ++mf) {
        int row = wr * 64 + mf * 16 + j;
        af[mf] = *(const bf16x8*)(As + row * 128 + SWZ(row, k2 * 64 + g * 16));
      }
      #pragma unroll
      for (int nf = 0; nf < 4; ++nf) {
        int row = wc * 64 + nf * 16 + j;
        bfr[nf] = *(const bf16x8*)(Bs + row * 128 + SWZ(row, k2 * 64 + g * 16));
      }
      #pragma unroll
      for (int mf = 0; mf < 4; ++mf)
        #pragma unroll
        for (int nf = 0; nf < 4; ++nf)
          acc[mf][nf] = __builtin_amdgcn_mfma_f32_16x16x32_bf16(af[mf], bfr[nf], acc[mf][nf], 0, 0, 0);
    }
  }

  #pragma unroll
  for (int mf = 0; mf < 4; ++mf) {
    #pragma unroll
    for (int rr = 0; rr < 4; ++rr) {
      int m = m0 + wr * 64 + mf * 16 + g * 4 + rr;
      float bm = bias[m];
      #pragma unroll
      for (int nf = 0; nf < 4; ++nf) {
        int n = n0 + wc * 64 + nf * 16 + j;
        Cp[(size_t)m * 2048 + n] = acc[mf][nf][rr] + bm;
      }
    }
  }
}

// ---------------- flash attention v3: 32 rows/wave, 1024 blocks, static max ----
// QT (pre-scaled by CL), KT: [B][2048][1024] bf16; V: [B][1024][2048] bf16.
// grid 1024 (XCD-grouped), block 256 = 4 waves x 32 q-rows.
__global__ __launch_bounds__(256, 3) void attn_kernel3(const unsigned short* __restrict__ QT,
                                                       const unsigned short* __restrict__ KT,
                                                       const unsigned short* __restrict__ V,
                                                       unsigned short* __restrict__ OT) {
  __shared__ __align__(16) char Ks[8192];   // K tile [64 s][64 k] bf16, swizzled
  __shared__ __align__(16) char Vs[8192];   // V tile [64 ko][64 s] bf16, swizzled
  __shared__ float lbuf[4][32];

  const int fid = blockIdx.x;              // 0..1023
  const int xcd = fid & 7, idx = fid >> 3;
  const int bh = ((idx & 7) << 3) | xcd;   // 8 bh per XCD
  const int tblk = idx >> 3;               // 0..15
  const int b = bh >> 4, h = bh & 15;

  const int tid = threadIdx.x;
  const int w = tid >> 6, l = tid & 63, lo5 = l & 31, hi = l >> 5;
  const int tq0 = tblk * 128 + w * 32;

  // Q fragments (B-operand): lane holds q-row (tq0+lo5), k = kb*16+hi*8..+7
  bf16x8 q[4];
  {
    const unsigned short* Qb = QT + ((size_t)(b * 2048 + tq0 + lo5)) * 1024 + h * 64 + hi * 8;
    #pragma unroll
    for (int kb = 0; kb < 4; ++kb) q[kb] = *(const bf16x8*)(Qb + kb * 16);
  }

  f32x16 o[2] = {};
  float lr = 0.f;

  // staging coords (fixed per thread): 2 passes of 256 threads -> 64 rows x 8 slots
  const int srow0 = tid >> 3, sslot = tid & 7;
  const unsigned short* Kg0 = KT + ((size_t)b * 2048) * 1024 + h * 64;
  const unsigned short* Vg0 = V + ((size_t)(b * 1024 + h * 64)) * 2048;

  for (int s0 = 0; s0 < 2048; s0 += 64) {
    __syncthreads();
    #pragma unroll
    for (int p = 0; p < 2; ++p) {
      int row = p * 32 + srow0;
      int ch = sslot ^ (row & 7);
      GLOAD_LDS16(Kg0 + (size_t)(s0 + row) * 1024 + ch * 8, Ks + (p * 256 + tid) * 16);
      GLOAD_LDS16(Vg0 + (size_t)row * 2048 + s0 + ch * 8, Vs + (p * 256 + tid) * 16);
    }
    __syncthreads();

    // QK^T (swapped): p0 = s rows 0..31, p1 = s rows 32..63; col = lane&31 = t
    f32x16 p0 = {}, p1 = {};
    #pragma unroll
    for (int kb = 0; kb < 4; ++kb) {
      int r0 = lo5, r1 = 32 + lo5;
      bf16x8 ka0 = *(const bf16x8*)(Ks + r0 * 128 + SWZ(r0, kb * 32 + hi * 16));
      bf16x8 ka1 = *(const bf16x8*)(Ks + r1 * 128 + SWZ(r1, kb * 32 + hi * 16));
      p0 = __builtin_amdgcn_mfma_f32_32x32x16_bf16(ka0, q[kb], p0, 0, 0, 0);
      p1 = __builtin_amdgcn_mfma_f32_32x32x16_bf16(ka1, q[kb], p1, 0, 0, 0);
    }

    // softmax, static m=0 (scores pre-scaled by CL at the Q projection)
    float ls0 = 0.f, ls1 = 0.f, ls2 = 0.f, ls3 = 0.f;
    #pragma unroll
    for (int r = 0; r < 16; r += 4) {
      float e0 = fexp2(p0[r]), e1 = fexp2(p0[r + 1]), e2 = fexp2(p0[r + 2]), e3 = fexp2(p0[r + 3]);
      p0[r] = e0; p0[r + 1] = e1; p0[r + 2] = e2; p0[r + 3] = e3;
      ls0 += e0; ls1 += e1; ls2 += e2; ls3 += e3;
    }
    #pragma unroll
    for (int r = 0; r < 16; r += 4) {
      float e0 = fexp2(p1[r]), e1 = fexp2(p1[r + 1]), e2 = fexp2(p1[r + 2]), e3 = fexp2(p1[r + 3]);
      p1[r] = e0; p1[r + 1] = e1; p1[r + 2] = e2; p1[r + 3] = e3;
      ls0 += e0; ls1 += e1; ls2 += e2; ls3 += e3;
    }
    lr += (ls0 + ls1) + (ls2 + ls3);

    // pack P -> bf16 A-frags via cvt_pk + permlane32_swap
    u32x4 pa[4];
    {
      u32x2 ra = plswap(cvtpk(p0[0], p0[1]), cvtpk(p0[4], p0[5]));
      u32x2 rb = plswap(cvtpk(p0[2], p0[3]), cvtpk(p0[6], p0[7]));
      pa[0] = (u32x4){ra[0], rb[0], ra[1], rb[1]};
      u32x2 rc = plswap(cvtpk(p0[8], p0[9]), cvtpk(p0[12], p0[13]));
      u32x2 rd = plswap(cvtpk(p0[10], p0[11]), cvtpk(p0[14], p0[15]));
      pa[1] = (u32x4){rc[0], rd[0], rc[1], rd[1]};
      u32x2 re = plswap(cvtpk(p1[0], p1[1]), cvtpk(p1[4], p1[5]));
      u32x2 rf = plswap(cvtpk(p1[2], p1[3]), cvtpk(p1[6], p1[7]));
      pa[2] = (u32x4){re[0], rf[0], re[1], rf[1]};
      u32x2 rg = plswap(cvtpk(p1[8], p1[9]), cvtpk(p1[12], p1[13]));
      u32x2 rh = plswap(cvtpk(p1[10], p1[11]), cvtpk(p1[14], p1[15]));
      pa[3] = (u32x4){rg[0], rh[0], rg[1], rh[1]};
    }

    // PV: o[kb2] += P * V^T
    #pragma unroll
    for (int sb = 0; sb < 4; ++sb)
      #pragma unroll
      for (int kb2 = 0; kb2 < 2; ++kb2) {
        int row = kb2 * 32 + lo5;
        bf16x8 vb = *(const bf16x8*)(Vs + row * 128 + SWZ(row, sb * 32 + hi * 16));
        o[kb2] = __builtin_amdgcn_mfma_f32_32x32x16_bf16(
            __builtin_bit_cast(bf16x8, pa[sb]), vb, o[kb2], 0, 0, 0);
      }
  }

  // epilogue: combine row-sums across lane pair, broadcast 1/l, store
  u32x2 sw = plswap(__float_as_uint(lr), __float_as_uint(lr));
  float lt = __uint_as_float(sw[0]) + __uint_as_float(sw[1]);
  if (hi == 0) lbuf[w][lo5] = 1.0f / lt;
  unsigned short* Ob = OT + ((size_t)(b * 2048 + tq0)) * 1024 + h * 64 + lo5;
  #pragma unroll
  for (int r = 0; r < 16; ++r) {
    int srow = (r & 3) + 8 * (r >> 2) + 4 * hi;
    float inv = lbuf[w][srow];
    Ob[(size_t)srow * 1024 + 0]  = f2bf(o[0][r] * inv);
    Ob[(size_t)srow * 1024 + 32] = f2bf(o[1][r] * inv);
  }
}

// ---------------- launch ----------------
extern "C" void kernel_launch(void* const* d_in, const int* in_sizes, int n_in,
                              void* d_out, int out_size, void* d_ws, size_t ws_size,
                              hipStream_t stream) {
  const float* x  = (const float*)d_in[0];
  const float* c  = (const float*)d_in[1];
  const float* Wq = (const float*)d_in[2];
  const float* bq = (const float*)d_in[3];
  const float* Wk = (const float*)d_in[4];
  const float* bk = (const float*)d_in[5];
  const float* Wv = (const float*)d_in[6];
  const float* bv = (const float*)d_in[7];
  const float* Wo = (const float*)d_in[8];
  const float* bo = (const float*)d_in[9];

  const size_t MB = 1024 * 1024;
  char* ws = (char*)d_ws;
  unsigned short* wqb = (unsigned short*)(ws + 0 * MB);
  unsigned short* wkb = (unsigned short*)(ws + 2 * MB);
  unsigned short* wvb = (unsigned short*)(ws + 4 * MB);
  unsigned short* wob = (unsigned short*)(ws + 6 * MB);
  unsigned short* xT  = (unsigned short*)(ws + 8 * MB);   // [B][T][C] bf16, 16MB
  unsigned short* cT  = (unsigned short*)(ws + 24 * MB);
  unsigned short* QT  = (unsigned short*)(ws + 40 * MB);
  unsigned short* KT  = (unsigned short*)(ws + 56 * MB);
  unsigned short* Vb  = (unsigned short*)(ws + 72 * MB);  // [B][C][T] bf16
  unsigned short* OT  = xT;  // reuse: x dead after QKV gemm

  cvt_f32_bf16<<<1024, 256, 0, stream>>>(Wq, wqb, 1 << 20, CL);   // fold scale*log2e
  cvt_f32_bf16<<<1024, 256, 0, stream>>>(Wk, wkb, 1 << 20, 1.0f);
  cvt_f32_bf16<<<1024, 256, 0, stream>>>(Wv, wvb, 1 << 20, 1.0f);
  cvt_f32_bf16<<<1024, 256, 0, stream>>>(Wo, wob, 1 << 20, 1.0f);
  transpose_cvt<<<dim3(64, 32, 4), 256, 0, stream>>>(x, xT, 1024, 2048);
  transpose_cvt<<<dim3(64, 32, 4), 256, 0, stream>>>(c, cT, 1024, 2048);

  qkv_gemm<<<dim3(1536), 256, 0, stream>>>(xT, cT, wqb, wkb, wvb, bq, bk, bv, QT, KT, Vb);

  attn_kernel3<<<dim3(1024), 256, 0, stream>>>(QT, KT, Vb, OT);

  gemm_out<<<dim3(16, 8, 4), 256, 0, stream>>>(wob, OT, (float*)d_out, bo);
}

// Round 4
// 205.771 us; speedup vs baseline: 1.8261x; 1.0790x over previous
//
#include <hip/hip_runtime.h>
#include <stdint.h>

typedef __bf16 bf16x8 __attribute__((ext_vector_type(8)));
typedef float f32x4 __attribute__((ext_vector_type(4)));
typedef float f32x16 __attribute__((ext_vector_type(16)));
typedef unsigned u32x2 __attribute__((ext_vector_type(2)));
typedef unsigned u32x4 __attribute__((ext_vector_type(4)));

#define LOG2E 1.44269504088896340736f
#define ATT_SCALE 0.125f
#define CL (ATT_SCALE * LOG2E)
#define SWZ(row, colb) ((colb) ^ (((row) & 7) << 4))

#define GLOAD_LDS16(gp, lp)                                                  \
  __builtin_amdgcn_global_load_lds(                                          \
      (const __attribute__((address_space(1))) void*)(gp),                   \
      (__attribute__((address_space(3))) void*)(lp), 16, 0, 0)

__device__ __forceinline__ unsigned short f2bf(float f) {
  unsigned int x = __float_as_uint(f);
  x += 0x7fffu + ((x >> 16) & 1u);
  return (unsigned short)(x >> 16);
}

__device__ __forceinline__ float fexp2(float x) {
#if __has_builtin(__builtin_amdgcn_exp2f)
  return __builtin_amdgcn_exp2f(x);
#else
  return exp2f(x);
#endif
}

__device__ __forceinline__ unsigned cvtpk(float lo, float hi) {
  unsigned r;
  asm("v_cvt_pk_bf16_f32 %0, %1, %2" : "=v"(r) : "v"(lo), "v"(hi));
  return r;
}

__device__ __forceinline__ u32x2 plswap(unsigned a, unsigned b) {
#if __has_builtin(__builtin_amdgcn_permlane32_swap)
  return __builtin_amdgcn_permlane32_swap(a, b, false, false);
#else
  unsigned ax = (unsigned)__shfl_xor((int)a, 32);
  unsigned bx = (unsigned)__shfl_xor((int)b, 32);
  int hi = (threadIdx.x & 32) ? 1 : 0;
  u32x2 r;
  r[0] = hi ? bx : a;
  r[1] = hi ? b : ax;
  return r;
#endif
}

// ---------------- all 4 weight converts in one dispatch ----------------
__global__ __launch_bounds__(256) void cvt_weights(
    const float* __restrict__ w0, const float* __restrict__ w1,
    const float* __restrict__ w2, const float* __restrict__ w3,
    unsigned short* __restrict__ o0, unsigned short* __restrict__ o1,
    unsigned short* __restrict__ o2, unsigned short* __restrict__ o3) {
  int sel = blockIdx.x >> 10;
  const float* in = sel == 0 ? w0 : sel == 1 ? w1 : sel == 2 ? w2 : w3;
  unsigned short* out = sel == 0 ? o0 : sel == 1 ? o1 : sel == 2 ? o2 : o3;
  float scale = sel == 0 ? CL : 1.0f;   // fold softmax scale*log2e into Wq
  int i = ((blockIdx.x & 1023) * 256 + threadIdx.x) * 4;
  float4 v = *(const float4*)(in + i);
  ushort4 o;
  o.x = f2bf(v.x * scale); o.y = f2bf(v.y * scale);
  o.z = f2bf(v.z * scale); o.w = f2bf(v.w * scale);
  *(ushort4*)(out + i) = o;
}

// ---------------- [B][C][T] f32 -> [B][T][C] bf16 transpose (x and c) --------
__global__ __launch_bounds__(256) void transpose_cvt2(const float* __restrict__ x,
                                                      const float* __restrict__ c,
                                                      unsigned short* __restrict__ xT,
                                                      unsigned short* __restrict__ cT) {
  __shared__ unsigned short tile[32][33];
  const int C = 1024, T = 2048;
  int z = blockIdx.z;
  const float* in = (z < 4) ? x : c;
  unsigned short* out = (z < 4) ? xT : cT;
  int b = z & 3;
  int t0 = blockIdx.x * 32, c0 = blockIdx.y * 32;
  int tx = threadIdx.x & 31, ty = threadIdx.x >> 5;
  const float* src = in + ((size_t)b * C + c0) * T + t0;
  #pragma unroll
  for (int i = 0; i < 4; ++i) {
    int cc = ty + i * 8;
    tile[cc][tx] = f2bf(src[(size_t)cc * T + tx]);
  }
  __syncthreads();
  unsigned short* dst = out + ((size_t)b * T + t0) * C + c0;
  #pragma unroll
  for (int i = 0; i < 4; ++i) {
    int tt = ty + i * 8;
    dst[(size_t)tt * C + tx] = tile[tx][tt];
  }
}

// ---------------- fused QKV GEMM, 2-phase double-buffered pipeline ----------
// op0: QT[t][o] = xT[t][c]*Wq[o][c]*CL + bq*CL ; op1: KT = cT*Wk + bk ;
// op2: Vb[o][t] = Wv[o][c]*cT[t][c] + bv. grid 1536 1-D, XCD-chunked.
__global__ __launch_bounds__(256) void qkv_gemm(
    const unsigned short* __restrict__ xT, const unsigned short* __restrict__ cT,
    const unsigned short* __restrict__ wq, const unsigned short* __restrict__ wk,
    const unsigned short* __restrict__ wv,
    const float* __restrict__ bq, const float* __restrict__ bk,
    const float* __restrict__ bv,
    unsigned short* __restrict__ QT, unsigned short* __restrict__ KT,
    unsigned short* __restrict__ Vb) {
  __shared__ __align__(16) char lds[2][32768];   // [buf][As 16K | Bs 16K]
  const size_t sBT = (size_t)2048 * 1024;

  const int id = (blockIdx.x & 7) * 192 + (blockIdx.x >> 3);  // XCD chunking
  const int op = id >> 9;
  const int r = id & 511;
  const int z = r >> 7;
  const unsigned short *A, *Bw;
  unsigned short* Cp;
  const float* bias;
  int m0, n0, ldC, bias_is_m;
  float bs;
  if (op == 2) {
    n0 = (r & 15) * 128; m0 = ((r >> 4) & 7) * 128;
    A = wv; Bw = cT + z * sBT; Cp = Vb + z * (size_t)1024 * 2048;
    bias = bv; ldC = 2048; bias_is_m = 1; bs = 1.0f;
  } else {
    n0 = (r & 7) * 128; m0 = ((r >> 3) & 15) * 128;
    A = (op == 0 ? xT : cT) + z * sBT;
    Bw = (op == 0 ? wq : wk);
    Cp = (op == 0 ? QT : KT) + z * sBT;
    bias = (op == 0 ? bq : bk); ldC = 1024; bias_is_m = 0;
    bs = (op == 0) ? CL : 1.0f;
  }

  const int tid = threadIdx.x;
  const int l = tid & 63, w = tid >> 6;
  const int g = l >> 4, j = l & 15;
  const int wr = w >> 1, wc = w & 1;
  const int srow = tid >> 3, sslot = tid & 7;

  f32x4 acc[4][4] = {};

  auto stage = [&](int bsel, int k0) {
    char* As = lds[bsel];
    char* Bs = lds[bsel] + 16384;
    #pragma unroll
    for (int p = 0; p < 4; ++p) {
      int row = p * 32 + srow;
      int ch = sslot ^ (row & 7);
      GLOAD_LDS16(A + (size_t)(m0 + row) * 1024 + k0 + ch * 8, As + (p * 256 + tid) * 16);
      GLOAD_LDS16(Bw + (size_t)(n0 + row) * 1024 + k0 + ch * 8, Bs + (p * 256 + tid) * 16);
    }
  };

  stage(0, 0);
  __syncthreads();

  for (int t = 0; t < 16; ++t) {
    int cur = t & 1;
    if (t < 15) stage(cur ^ 1, (t + 1) * 64);   // issue next tile BEFORE compute
    char* As = lds[cur];
    char* Bs = lds[cur] + 16384;
    #pragma unroll
    for (int k2 = 0; k2 < 2; ++k2) {
      bf16x8 af[4], bfr[4];
      #pragma unroll
      for (int mf = 0; mf < 4; ++mf) {
        int row = wr * 64 + mf * 16 + j;
        af[mf] = *(const bf16x8*)(As + row * 128 + SWZ(row, k2 * 64 + g * 16));
      }
      #pragma unroll
      for (int nf = 0; nf < 4; ++nf) {
        int row = wc * 64 + nf * 16 + j;
        bfr[nf] = *(const bf16x8*)(Bs + row * 128 + SWZ(row, k2 * 64 + g * 16));
      }
      #pragma unroll
      for (int mf = 0; mf < 4; ++mf)
        #pragma unroll
        for (int nf = 0; nf < 4; ++nf)
          acc[mf][nf] = __builtin_amdgcn_mfma_f32_16x16x32_bf16(af[mf], bfr[nf], acc[mf][nf], 0, 0, 0);
    }
    __syncthreads();   // drains this iter's prefetch AFTER compute covered it
  }

  #pragma unroll
  for (int mf = 0; mf < 4; ++mf) {
    #pragma unroll
    for (int rr = 0; rr < 4; ++rr) {
      int m = m0 + wr * 64 + mf * 16 + g * 4 + rr;
      float bm = bias_is_m ? bias[m] * bs : 0.f;
      #pragma unroll
      for (int nf = 0; nf < 4; ++nf) {
        int n = n0 + wc * 64 + nf * 16 + j;
        float val = acc[mf][nf][rr] + bm + (bias_is_m ? 0.f : bias[n] * bs);
        Cp[(size_t)m * ldC + n] = f2bf(val);
      }
    }
  }
}

// ---------------- output projection GEMM: fp32 out, 2-phase pipeline --------
__global__ __launch_bounds__(256) void gemm_out(
    const unsigned short* __restrict__ Wo, const unsigned short* __restrict__ OT,
    float* __restrict__ Out, const float* __restrict__ bias) {
  __shared__ __align__(16) char lds[2][32768];
  const size_t sBT = (size_t)2048 * 1024;
  const int z = blockIdx.z;
  const int m0 = blockIdx.y * 128, n0 = blockIdx.x * 128;
  const unsigned short* A = Wo;
  const unsigned short* B = OT + z * sBT;
  float* Cp = Out + z * (size_t)1024 * 2048;

  const int tid = threadIdx.x;
  const int l = tid & 63, w = tid >> 6;
  const int g = l >> 4, j = l & 15;
  const int wr = w >> 1, wc = w & 1;
  const int srow = tid >> 3, sslot = tid & 7;

  f32x4 acc[4][4] = {};

  auto stage = [&](int bsel, int k0) {
    char* As = lds[bsel];
    char* Bs = lds[bsel] + 16384;
    #pragma unroll
    for (int p = 0; p < 4; ++p) {
      int row = p * 32 + srow;
      int ch = sslot ^ (row & 7);
      GLOAD_LDS16(A + (size_t)(m0 + row) * 1024 + k0 + ch * 8, As + (p * 256 + tid) * 16);
      GLOAD_LDS16(B + (size_t)(n0 + row) * 1024 + k0 + ch * 8, Bs + (p * 256 + tid) * 16);
    }
  };

  stage(0, 0);
  __syncthreads();

  for (int t = 0; t < 16; ++t) {
    int cur = t & 1;
    if (t < 15) stage(cur ^ 1, (t + 1) * 64);
    char* As = lds[cur];
    char* Bs = lds[cur] + 16384;
    #pragma unroll
    for (int k2 = 0; k2 < 2; ++k2) {
      bf16x8 af[4], bfr[4];
      #pragma unroll
      for (int mf = 0; mf < 4; ++mf) {
        int row = wr * 64 + mf * 16 + j;
        af[mf] = *(const bf16x8*)(As + row * 128 + SWZ(row, k2 * 64 + g * 16));
      }
      #pragma unroll
      for (int nf = 0; nf < 4; ++nf) {
        int row = wc * 64 + nf * 16 + j;
        bfr[nf] = *(const bf16x8*)(Bs + row * 128 + SWZ(row, k2 * 64 + g * 16));
      }
      #pragma unroll
      for (int mf = 0; mf < 4; ++mf)
        #pragma unroll
        for (int nf = 0; nf < 4; ++nf)
          acc[mf][nf] = __builtin_amdgcn_mfma_f32_16x16x32_bf16(af[mf], bfr[nf], acc[mf][nf], 0, 0, 0);
    }
    __syncthreads();
  }

  #pragma unroll
  for (int mf = 0; mf < 4; ++mf) {
    #pragma unroll
    for (int rr = 0; rr < 4; ++rr) {
      int m = m0 + wr * 64 + mf * 16 + g * 4 + rr;
      float bm = bias[m];
      #pragma unroll
      for (int nf = 0; nf < 4; ++nf) {
        int n = n0 + wc * 64 + nf * 16 + j;
        Cp[(size_t)m * 2048 + n] = acc[mf][nf][rr] + bm;
      }
    }
  }
}

// ---------------- flash attention v4: 2-phase double-buffered K/V -----------
// QT (pre-scaled by CL), KT: [B][2048][1024] bf16; V: [B][1024][2048] bf16.
// grid 1024 (XCD-grouped), block 256 = 4 waves x 32 q-rows.
__global__ __launch_bounds__(256, 3) void attn_kernel4(const unsigned short* __restrict__ QT,
                                                       const unsigned short* __restrict__ KT,
                                                       const unsigned short* __restrict__ V,
                                                       unsigned short* __restrict__ OT) {
  __shared__ __align__(16) char kv[2][16384];   // [buf][Ks 8K | Vs 8K]
  __shared__ float lbuf[4][32];

  const int fid = blockIdx.x;              // 0..1023
  const int xcd = fid & 7, idx = fid >> 3;
  const int bh = ((idx & 7) << 3) | xcd;   // 8 bh per XCD
  const int tblk = idx >> 3;               // 0..15
  const int b = bh >> 4, h = bh & 15;

  const int tid = threadIdx.x;
  const int w = tid >> 6, l = tid & 63, lo5 = l & 31, hi = l >> 5;
  const int tq0 = tblk * 128 + w * 32;

  bf16x8 q[4];
  {
    const unsigned short* Qb = QT + ((size_t)(b * 2048 + tq0 + lo5)) * 1024 + h * 64 + hi * 8;
    #pragma unroll
    for (int kb = 0; kb < 4; ++kb) q[kb] = *(const bf16x8*)(Qb + kb * 16);
  }

  f32x16 o[2] = {};
  float lr = 0.f;

  const int srow0 = tid >> 3, sslot = tid & 7;
  const unsigned short* Kg0 = KT + ((size_t)b * 2048) * 1024 + h * 64;
  const unsigned short* Vg0 = V + ((size_t)(b * 1024 + h * 64)) * 2048;

  auto stage = [&](int bsel, int s0) {
    char* Ks = kv[bsel];
    char* Vs = kv[bsel] + 8192;
    #pragma unroll
    for (int p = 0; p < 2; ++p) {
      int row = p * 32 + srow0;
      int ch = sslot ^ (row & 7);
      GLOAD_LDS16(Kg0 + (size_t)(s0 + row) * 1024 + ch * 8, Ks + (p * 256 + tid) * 16);
      GLOAD_LDS16(Vg0 + (size_t)row * 2048 + s0 + ch * 8, Vs + (p * 256 + tid) * 16);
    }
  };

  stage(0, 0);
  __syncthreads();

  for (int t = 0; t < 32; ++t) {
    int cur = t & 1;
    if (t < 31) stage(cur ^ 1, (t + 1) * 64);
    char* Ks = kv[cur];
    char* Vs = kv[cur] + 8192;

    // QK^T (swapped): p0 = s rows 0..31, p1 = s rows 32..63; col = lane&31 = t
    f32x16 p0 = {}, p1 = {};
    #pragma unroll
    for (int kb = 0; kb < 4; ++kb) {
      int r0 = lo5, r1 = 32 + lo5;
      bf16x8 ka0 = *(const bf16x8*)(Ks + r0 * 128 + SWZ(r0, kb * 32 + hi * 16));
      bf16x8 ka1 = *(const bf16x8*)(Ks + r1 * 128 + SWZ(r1, kb * 32 + hi * 16));
      p0 = __builtin_amdgcn_mfma_f32_32x32x16_bf16(ka0, q[kb], p0, 0, 0, 0);
      p1 = __builtin_amdgcn_mfma_f32_32x32x16_bf16(ka1, q[kb], p1, 0, 0, 0);
    }

    // softmax, static m=0 (scores pre-scaled by CL at the Q projection)
    float ls0 = 0.f, ls1 = 0.f, ls2 = 0.f, ls3 = 0.f;
    #pragma unroll
    for (int r = 0; r < 16; r += 4) {
      float e0 = fexp2(p0[r]), e1 = fexp2(p0[r + 1]), e2 = fexp2(p0[r + 2]), e3 = fexp2(p0[r + 3]);
      p0[r] = e0; p0[r + 1] = e1; p0[r + 2] = e2; p0[r + 3] = e3;
      ls0 += e0; ls1 += e1; ls2 += e2; ls3 += e3;
    }
    #pragma unroll
    for (int r = 0; r < 16; r += 4) {
      float e0 = fexp2(p1[r]), e1 = fexp2(p1[r + 1]), e2 = fexp2(p1[r + 2]), e3 = fexp2(p1[r + 3]);
      p1[r] = e0; p1[r + 1] = e1; p1[r + 2] = e2; p1[r + 3] = e3;
      ls0 += e0; ls1 += e1; ls2 += e2; ls3 += e3;
    }
    lr += (ls0 + ls1) + (ls2 + ls3);

    // pack P -> bf16 A-frags via cvt_pk + permlane32_swap
    u32x4 pa[4];
    {
      u32x2 ra = plswap(cvtpk(p0[0], p0[1]), cvtpk(p0[4], p0[5]));
      u32x2 rb = plswap(cvtpk(p0[2], p0[3]), cvtpk(p0[6], p0[7]));
      pa[0] = (u32x4){ra[0], rb[0], ra[1], rb[1]};
      u32x2 rc = plswap(cvtpk(p0[8], p0[9]), cvtpk(p0[12], p0[13]));
      u32x2 rd = plswap(cvtpk(p0[10], p0[11]), cvtpk(p0[14], p0[15]));
      pa[1] = (u32x4){rc[0], rd[0], rc[1], rd[1]};
      u32x2 re = plswap(cvtpk(p1[0], p1[1]), cvtpk(p1[4], p1[5]));
      u32x2 rf = plswap(cvtpk(p1[2], p1[3]), cvtpk(p1[6], p1[7]));
      pa[2] = (u32x4){re[0], rf[0], re[1], rf[1]};
      u32x2 rg = plswap(cvtpk(p1[8], p1[9]), cvtpk(p1[12], p1[13]));
      u32x2 rh = plswap(cvtpk(p1[10], p1[11]), cvtpk(p1[14], p1[15]));
      pa[3] = (u32x4){rg[0], rh[0], rg[1], rh[1]};
    }

    // PV: o[kb2] += P * V^T
    #pragma unroll
    for (int sb = 0; sb < 4; ++sb)
      #pragma unroll
      for (int kb2 = 0; kb2 < 2; ++kb2) {
        int row = kb2 * 32 + lo5;
        bf16x8 vb = *(const bf16x8*)(Vs + row * 128 + SWZ(row, sb * 32 + hi * 16));
        o[kb2] = __builtin_amdgcn_mfma_f32_32x32x16_bf16(
            __builtin_bit_cast(bf16x8, pa[sb]), vb, o[kb2], 0, 0, 0);
      }
    __syncthreads();
  }

  // epilogue: combine row-sums across lane pair, broadcast 1/l, store
  u32x2 sw = plswap(__float_as_uint(lr), __float_as_uint(lr));
  float lt = __uint_as_float(sw[0]) + __uint_as_float(sw[1]);
  if (hi == 0) lbuf[w][lo5] = 1.0f / lt;
  unsigned short* Ob = OT + ((size_t)(b * 2048 + tq0)) * 1024 + h * 64 + lo5;
  #pragma unroll
  for (int r = 0; r < 16; ++r) {
    int srow = (r & 3) + 8 * (r >> 2) + 4 * hi;
    float inv = lbuf[w][srow];
    Ob[(size_t)srow * 1024 + 0]  = f2bf(o[0][r] * inv);
    Ob[(size_t)srow * 1024 + 32] = f2bf(o[1][r] * inv);
  }
}

// ---------------- launch ----------------
extern "C" void kernel_launch(void* const* d_in, const int* in_sizes, int n_in,
                              void* d_out, int out_size, void* d_ws, size_t ws_size,
                              hipStream_t stream) {
  const float* x  = (const float*)d_in[0];
  const float* c  = (const float*)d_in[1];
  const float* Wq = (const float*)d_in[2];
  const float* bq = (const float*)d_in[3];
  const float* Wk = (const float*)d_in[4];
  const float* bk = (const float*)d_in[5];
  const float* Wv = (const float*)d_in[6];
  const float* bv = (const float*)d_in[7];
  const float* Wo = (const float*)d_in[8];
  const float* bo = (const float*)d_in[9];

  const size_t MB = 1024 * 1024;
  char* ws = (char*)d_ws;
  unsigned short* wqb = (unsigned short*)(ws + 0 * MB);
  unsigned short* wkb = (unsigned short*)(ws + 2 * MB);
  unsigned short* wvb = (unsigned short*)(ws + 4 * MB);
  unsigned short* wob = (unsigned short*)(ws + 6 * MB);
  unsigned short* xT  = (unsigned short*)(ws + 8 * MB);   // [B][T][C] bf16, 16MB
  unsigned short* cT  = (unsigned short*)(ws + 24 * MB);
  unsigned short* QT  = (unsigned short*)(ws + 40 * MB);
  unsigned short* KT  = (unsigned short*)(ws + 56 * MB);
  unsigned short* Vb  = (unsigned short*)(ws + 72 * MB);  // [B][C][T] bf16
  unsigned short* OT  = xT;  // reuse: x dead after QKV gemm

  cvt_weights<<<dim3(4096), 256, 0, stream>>>(Wq, Wk, Wv, Wo, wqb, wkb, wvb, wob);
  transpose_cvt2<<<dim3(64, 32, 8), 256, 0, stream>>>(x, c, xT, cT);

  qkv_gemm<<<dim3(1536), 256, 0, stream>>>(xT, cT, wqb, wkb, wvb, bq, bk, bv, QT, KT, Vb);

  attn_kernel4<<<dim3(1024), 256, 0, stream>>>(QT, KT, Vb, OT);

  gemm_out<<<dim3(16, 8, 4), 256, 0, stream>>>(wob, OT, (float*)d_out, bo);
}